// Round 8
// baseline (191.282 us; speedup 1.0000x reference)
//
#include <hip/hip_runtime.h>

#define NB 8192
#define ND 128
#define MARGINF 0.3f
#define FLTMAX 3.402823466e+38f
#define GRID_BLKS 512
#define NWAVES (GRID_BLKS * 4)
#define A_TILES 16            // 16 mini-tiles x 16 cols = 256 cols in phase A
#define SCALEQ 33554432.0     // 2^25 quantizer -> integer atomics, deterministic

// ws layout (bytes):
//   [0]  uint bar   [4] uint cnt   [8] uint done   [16] u64 acc
//   [64]    int   list[8192]
//   [32832] float dapw[8192]
//   [65600] uint  rem[8192]
//   [98368] u64   idxval[8192]   (packed (col<<32)|float_bits; 0xFFFFFFFE = diag)

__device__ __forceinline__ float dot4(float4 x, float4 y) {
    return x.x * y.x + x.y * y.y + x.z * y.z + x.w * y.w;
}

// Butterfly sum within each 32-lane half.
__device__ __forceinline__ float half_reduce(float v) {
    v += __shfl_xor(v, 1, 64);
    v += __shfl_xor(v, 2, 64);
    v += __shfl_xor(v, 4, 64);
    v += __shfl_xor(v, 8, 64);
    v += __shfl_xor(v, 16, 64);
    return v;
}

// Lane owning local column c: col(L) = 2*(L&31) + (L>>5).
__device__ __forceinline__ int owner(int c) {
    return (c & 1) ? 32 + (c >> 1) : (c >> 1);
}

__device__ __forceinline__ int first_col_from_mask(unsigned long long mask) {
    const unsigned int lo = (unsigned int)mask;          // even local cols
    const unsigned int hi = (unsigned int)(mask >> 32);  // odd local cols
    const int ce = lo ? 2 * (__ffs(lo) - 1)     : 0x7fffffff;
    const int co = hi ? 2 * (__ffs(hi) - 1) + 1 : 0x7fffffff;
    return ce < co ? ce : co;
}

__global__ void init_ws(unsigned int* __restrict__ hdr) {
    if (threadIdx.x == 0) {
        hdr[0] = 0u;                       // bar
        hdr[1] = 0u;                       // cnt
        hdr[2] = 0u;                       // done
        *(unsigned long long*)(hdr + 4) = 0ULL;   // acc (offset 16)
    }
}

// Device-wide barrier: all GRID_BLKS blocks co-resident by construction.
__device__ __forceinline__ void gbar(unsigned int* bar) {
    __syncthreads();
    __threadfence();                       // release all prior writes
    if (threadIdx.x == 0) {
        atomicAdd(bar, 1u);
        while (atomicAdd(bar, 0u) < GRID_BLKS) __builtin_amdgcn_s_sleep(8);
    }
    __syncthreads();
    __threadfence();                       // acquire: fresh view for all threads
}

__global__ __launch_bounds__(256, 2) void triplet_fused(const float* __restrict__ a,
                                                        const float* __restrict__ p,
                                                        const float* __restrict__ n,
                                                        float* __restrict__ out,
                                                        char* __restrict__ ws) {
    unsigned int*       bar    = (unsigned int*)ws;
    unsigned int*       cnt    = (unsigned int*)(ws + 4);
    unsigned int*       done   = (unsigned int*)(ws + 8);
    unsigned long long* acc    = (unsigned long long*)(ws + 16);
    int*                list   = (int*)(ws + 64);
    float*              dapw   = (float*)(ws + 32832);
    unsigned int*       rem    = (unsigned int*)(ws + 65600);
    unsigned long long* idxval = (unsigned long long*)(ws + 98368);

    __shared__ float s_part[4];
    const int tid  = threadIdx.x;
    const int wave = tid >> 6;
    const int lane = tid & 63;
    const int q    = lane & 31;
    const int h    = lane >> 5;
    const int gw   = blockIdx.x * 4 + wave;

    // ---- Phase A: 4 rows per wave, scan cols [0,256) with early exit ----
    float lsum = 0.f;
    for (int i = 0; i < 4; ++i) {
        const int row = gw * 4 + i;
        const float4 a4 = *(const float4*)(a + (size_t)row * ND + q * 4);
        const float4 p4 = *(const float4*)(p + (size_t)row * ND + q * 4);
        const float dist_ap = half_reduce(dot4(a4, p4));
        const float thresh  = dist_ap + MARGINF;
        bool resolved = false;
        for (int t = 0; t < A_TILES && !resolved; ++t) {
            float myval = FLTMAX;
            #pragma unroll
            for (int k = 0; k < 8; ++k) {
                const int col = t * 16 + 2 * k + h;
                const float4 nv = *(const float4*)(n + (size_t)col * ND + q * 4);
                const float v = half_reduce(dot4(a4, nv));
                if (q == k) myval = v;
            }
            const unsigned long long mask = __ballot(myval < thresh);
            if (mask) {  // wave-uniform
                const int c = first_col_from_mask(mask);
                const float dist_an = __shfl(myval, owner(c), 64);
                const float l = dist_an - dist_ap + MARGINF;
                lsum += l > 0.f ? l : 0.f;
                resolved = true;
            }
        }
        if (!resolved && lane == 0) {       // push to worklist (cnt pre-zeroed)
            const unsigned int k = atomicAdd(cnt, 1u);
            list[k]   = row;
            dapw[k]   = dist_ap;
            idxval[k] = ~0ULL;
            rem[k]    = 128u;
        }
    }
    if (lane == 0) s_part[wave] = lsum;
    __syncthreads();
    if (tid == 0) {
        const double bs = (double)s_part[0] + (double)s_part[1]
                        + (double)s_part[2] + (double)s_part[3];
        if (bs > 0.0) atomicAdd(acc, (unsigned long long)llrint(bs * SCALEQ));
    }

    gbar(bar);   // worklist + resolved losses complete, everywhere visible

    // ---- Phase B: (worklist row, 64-col chunk) pairs, one per wave-iter ----
    const unsigned int C = atomicAdd(cnt, 0u);
    const int npairs = (int)C * 128;
    for (int pair = gw; pair < npairs; pair += NWAVES) {
        const int w   = pair >> 7;
        const int tb  = (pair & 127) << 6;
        const int row = list[w];
        const float th = dapw[w] + MARGINF;
        const float4 a4 = *(const float4*)(a + (size_t)row * ND + q * 4);
        float myval = FLTMAX;
        #pragma unroll
        for (int k = 0; k < 32; ++k) {
            const int col = tb + 2 * k + h;
            const float4 nv = *(const float4*)(n + (size_t)col * ND + q * 4);
            const float v = half_reduce(dot4(a4, nv));   // bit-identical to A
            if (q == k) myval = v;
        }
        if (row >= tb && row < tb + 64) {                // diag candidate (fallback)
            const float dv = __shfl(myval, owner(row - tb), 64);
            if (lane == 0) {
                const unsigned long long dkey =
                    (0xFFFFFFFEULL << 32) | (unsigned long long)__float_as_uint(dv);
                atomicMin(&idxval[w], dkey);
            }
        }
        const unsigned long long mask = __ballot(myval < th);
        if (mask) {
            const int c = first_col_from_mask(mask);
            const float fv = __shfl(myval, owner(c), 64);
            if (lane == 0) {
                const unsigned long long key =
                    ((unsigned long long)(tb + c) << 32) | (unsigned long long)__float_as_uint(fv);
                atomicMin(&idxval[w], key);              // min col wins
            }
        }
        if (lane == 0) {
            const unsigned int old = atomicSub(&rem[w], 1u);
            if (old == 1u) {                             // last chunk for row w
                const unsigned long long u = atomicAdd(&idxval[w], 0ULL);
                const float an_v = __uint_as_float((unsigned int)u);  // hit or diag
                const float l = an_v - dapw[w] + MARGINF;
                if (l > 0.f)
                    atomicAdd(acc, (unsigned long long)llrint((double)l * SCALEQ));
            }
        }
    }

    // ---- Finale: last block writes the mean ----
    __syncthreads();
    if (tid == 0) {
        __threadfence();
        const unsigned int o = atomicAdd(done, 1u);
        if (o == GRID_BLKS - 1u) {
            __threadfence();
            const unsigned long long s = atomicAdd(acc, 0ULL);
            out[0] = (float)((double)s / SCALEQ / (double)NB);
        }
    }
}

extern "C" void kernel_launch(void* const* d_in, const int* in_sizes, int n_in,
                              void* d_out, int out_size, void* d_ws, size_t ws_size,
                              hipStream_t stream) {
    const float* a = (const float*)d_in[0];
    const float* p = (const float*)d_in[1];
    const float* n = (const float*)d_in[2];
    float* out = (float*)d_out;
    char*  wsb = (char*)d_ws;

    init_ws<<<1, 64, 0, stream>>>((unsigned int*)wsb);
    triplet_fused<<<GRID_BLKS, 256, 0, stream>>>(a, p, n, out, wsb);
}